// Round 21
// baseline (284.043 us; speedup 1.0000x reference)
//
#include <hip/hip_runtime.h>
#include <stdint.h>

#define DEV __device__ __forceinline__

typedef __bf16 bf16x8 __attribute__((ext_vector_type(8)));
typedef __bf16 bf16x4 __attribute__((ext_vector_type(4)));
typedef short s16x4 __attribute__((ext_vector_type(4)));
typedef float f32x4 __attribute__((ext_vector_type(4)));
typedef unsigned short u16;
typedef u16 u16x4v __attribute__((ext_vector_type(4)));
typedef u16 u16x8 __attribute__((ext_vector_type(8)));
typedef uint32_t u32;

static constexpr int Bb = 8, Tt = 1024, Dd = 1024, Hh = 16;
static constexpr int BT = Bb * Tt;      // 8192

// ---------- helpers ----------
DEV u16 f2bf(float f) {
  u32 u = __float_as_uint(f);
  u32 r = (u + 0x7FFFu + ((u >> 16) & 1u)) >> 16;
  return (u16)r;
}
DEV u32 cvtpk(float lo, float hi) {
  u32 r;
  asm("v_cvt_pk_bf16_f32 %0, %1, %2" : "=v"(r) : "v"(lo), "v"(hi));
  return r;
}
DEV void gload_lds16(const void* g, void* lds) {
  __builtin_amdgcn_global_load_lds(
      (const __attribute__((address_space(1))) void*)g,
      (__attribute__((address_space(3))) void*)lds,
      16, 0, 0);
}
DEV f32x4 MFMA16(bf16x4 a, bf16x4 b, f32x4 c) {
#if __has_builtin(__builtin_amdgcn_mfma_f32_16x16x16_bf16)
  return __builtin_amdgcn_mfma_f32_16x16x16_bf16(a, b, c, 0, 0, 0);
#elif __has_builtin(__builtin_amdgcn_mfma_f32_16x16x16bf16_1k)
  union { bf16x4 b; s16x4 s; } ua, ub;
  ua.b = a; ub.b = b;
  return __builtin_amdgcn_mfma_f32_16x16x16bf16_1k(ua.s, ub.s, c, 0, 0, 0);
#else
  asm("v_mfma_f32_16x16x16_bf16 %0, %1, %2, %0" : "+v"(c) : "v"(a), "v"(b));
  return c;
#endif
}

// ---------- fused converts: z=0 x, z=1 y, z=2..6 weights ----------
__global__ __launch_bounds__(256) void k_cvt(const float* __restrict__ x,
                                             const float* __restrict__ y,
                                             const float* __restrict__ Wq,
                                             const float* __restrict__ Wk,
                                             const float* __restrict__ Wv,
                                             const float* __restrict__ Wox,
                                             const float* __restrict__ Woy,
                                             u16* __restrict__ xb,
                                             u16* __restrict__ yb,
                                             u16* __restrict__ Wb) {
  const int z = blockIdx.z;
  const float* src;
  u16* dst;
  int n8;
  if (z == 0)      { src = x; dst = xb; n8 = BT * Dd / 8; }
  else if (z == 1) { src = y; dst = yb; n8 = BT * Dd / 8; }
  else {
    src = (z == 2) ? Wq : (z == 3) ? Wk : (z == 4) ? Wv : (z == 5) ? Wox : Woy;
    dst = Wb + (size_t)(z - 2) * (Dd * Dd);
    n8 = Dd * Dd / 8;
  }
  int i = blockIdx.x * blockDim.x + threadIdx.x;
  int stride = gridDim.x * blockDim.x;
  for (; i < n8; i += stride) {
    const float4* p = reinterpret_cast<const float4*>(src) + (size_t)i * 2;
    float4 a = p[0], b = p[1];
    u16x8 o;
    o[0] = f2bf(a.x); o[1] = f2bf(a.y); o[2] = f2bf(a.z); o[3] = f2bf(a.w);
    o[4] = f2bf(b.x); o[5] = f2bf(b.y); o[6] = f2bf(b.z); o[7] = f2bf(b.w);
    reinterpret_cast<u16x8*>(dst)[i] = o;
  }
}

// ---------- 256x256-tile 8-wave GEMM; faithful 8-phase template ----------
// 8 phases per 2 K-tiles; per phase the WHOLE block computes one C-quadrant
// (mh,nh) so A-half mh / B-half nh free early. One half-tile staged per phase,
// counted vmcnt(8)/(6) at 4 of 8 phases; queue never drains mid-loop.
template <int MODE, int GX, int GY>
__global__ __launch_bounds__(512, 2) void k_gemm256(
    const u16* __restrict__ xb, const u16* __restrict__ yb,
    const u16* __restrict__ W0,
    u16* __restrict__ Qb, u16* __restrict__ Kb, u16* __restrict__ Vtg,
    const float* __restrict__ bx, const float* __restrict__ by,
    float* __restrict__ out) {
  __shared__ alignas(16) u16 As[2][256 * 64];
  __shared__ alignas(16) u16 Bs[2][256 * 64];
  const int tid = threadIdx.x;
  const int l = tid & 63, wid = tid >> 6;
  const int wm = wid >> 2;   // 0..1 : 64-row group within quadrant
  const int wn = wid & 3;    // 0..3 : 32-col group within quadrant

  constexpr int NWG = GX * GY * 2;
  const int d0b = blockIdx.x;
  const int wk = (d0b & 7) * (NWG / 8) + (d0b >> 3);
  const int tz = wk / (GX * GY);
  const int rr = wk % (GX * GY);
  const int ty = rr / GX, tx = rr % GX;
  const int m0 = ty * 256, n0 = tx * 256;

  const u16* Ag;
  const u16* Wg;
  if constexpr (MODE == 0) {
    Ag = tz ? yb : xb;
    Wg = W0;
  } else {
    Ag = xb + tz * 64;                       // xb carries Ob
    Wg = W0 + (size_t)tz * (Dd * Dd);
  }

  auto stageA = [&](int buf, int kt, int half) {
#pragma unroll
    for (int i = 0; i < 2; ++i) {
      int idx = i * 512 + tid;
      int row = idx >> 3, P = idx & 7, G = P ^ (row & 7);
      const u16* src;
      if constexpr (MODE == 0) {
        src = Ag + (size_t)(m0 + half * 128 + row) * 1024 + kt * 64 + G * 8;
      } else {
        int m = m0 + half * 128 + row;
        src = Ag + ((size_t)((m >> 10) * 16 + kt) * 1024 + (m & 1023)) * 128 + G * 8;
      }
      gload_lds16(src, &As[buf][half * 8192 + idx * 8]);
    }
  };
  auto stageB = [&](int buf, int kt, int half) {
#pragma unroll
    for (int i = 0; i < 2; ++i) {
      int idx = i * 512 + tid;
      int row = idx >> 3, P = idx & 7, G = P ^ (row & 7);
      gload_lds16(Wg + (size_t)(n0 + half * 128 + row) * 1024 + kt * 64 + G * 8,
                  &Bs[buf][half * 8192 + idx * 8]);
    }
  };
  auto ldAq = [&](int bb, int MH, int m2, int kk) -> bf16x8 {
    int row = MH * 128 + wm * 64 + m2 * 16 + (l & 15);
    int P = (kk * 4 + (l >> 4)) ^ (row & 7);
    return *reinterpret_cast<const bf16x8*>(&As[bb][row * 64 + P * 8]);
  };
  auto ldBq = [&](int bb, int NH, int n2, int kk) -> bf16x8 {
    int row = NH * 128 + wn * 32 + n2 * 16 + (l & 15);
    int P = (kk * 4 + (l >> 4)) ^ (row & 7);
    return *reinterpret_cast<const bf16x8*>(&Bs[bb][row * 64 + P * 8]);
  };

  f32x4 acc[2][2][4][2] = {};   // [mh][nh][m2][n2]

  // prologue: K-tile0 full + K-tile1 halves A0,B0; one-time drain
  stageA(0, 0, 0); stageB(0, 0, 0); stageA(0, 0, 1); stageB(0, 0, 1);
  stageA(1, 1, 0); stageB(1, 1, 0);
  asm volatile("s_waitcnt vmcnt(0)" ::: "memory");
  __builtin_amdgcn_s_barrier();

#define RDA(bb, MH)                                                         \
  _Pragma("unroll") for (int m2 = 0; m2 < 4; ++m2)                          \
      _Pragma("unroll") for (int kk = 0; kk < 2; ++kk)                      \
          afr[m2][kk] = ldAq(bb, MH, m2, kk)
#define RDB(bb, NH)                                                         \
  _Pragma("unroll") for (int n2 = 0; n2 < 2; ++n2)                          \
      _Pragma("unroll") for (int kk = 0; kk < 2; ++kk)                      \
          bfr[n2][kk] = ldBq(bb, NH, n2, kk)
#define MM(MH, NH)                                                          \
  __builtin_amdgcn_s_barrier();                                             \
  asm volatile("s_waitcnt lgkmcnt(0)" ::: "memory");                        \
  __builtin_amdgcn_sched_barrier(0);                                        \
  __builtin_amdgcn_s_setprio(1);                                            \
  _Pragma("unroll") for (int m2 = 0; m2 < 4; ++m2)                          \
      _Pragma("unroll") for (int n2 = 0; n2 < 2; ++n2)                      \
          _Pragma("unroll") for (int kk = 0; kk < 2; ++kk)                  \
              acc[MH][NH][m2][n2] = __builtin_amdgcn_mfma_f32_16x16x32_bf16(\
                  afr[m2][kk], bfr[n2][kk], acc[MH][NH][m2][n2], 0, 0, 0);  \
  __builtin_amdgcn_s_setprio(0)
#define WAIT6 do { if (tail) asm volatile("s_waitcnt vmcnt(0)" ::: "memory"); \
                   else      asm volatile("s_waitcnt vmcnt(6)" ::: "memory"); } while (0)
#define WAIT8 do { if (tail) asm volatile("s_waitcnt vmcnt(0)" ::: "memory"); \
                   else      asm volatile("s_waitcnt vmcnt(8)" ::: "memory"); } while (0)
#define BAR __builtin_amdgcn_s_barrier()

  for (int it = 0; it < 8; ++it) {
    const int t0 = 2 * it;
    const bool tail = (it == 7);
    bf16x8 bfr[2][2], afr[4][2];

    // ---- P0: kt=t0 (buf0) Q(0,0); stage B1(t0+1)->buf1 ----
    RDB(0, 0); RDA(0, 0);
    stageB(1, t0 + 1, 1);
    MM(0, 0);
    WAIT6;
    BAR;
    // ---- P1: Q(1,0); stage A1(t0+1)->buf1 ----
    RDA(0, 1);
    stageA(1, t0 + 1, 1);
    MM(1, 0);
    BAR;
    // ---- P2: Q(0,1); stage B0(t0+2)->buf0 ----
    RDB(0, 1); RDA(0, 0);
    if (!tail) stageB(0, t0 + 2, 0);
    MM(0, 1);
    BAR;
    // ---- P3: Q(1,1); stage A0(t0+2)->buf0 ----
    RDA(0, 1);
    if (!tail) stageA(0, t0 + 2, 0);
    MM(1, 1);
    WAIT8;
    BAR;
    // ---- P4: kt=t0+1 (buf1) Q(0,0); stage B1(t0+2)->buf0 ----
    RDB(1, 0); RDA(1, 0);
    if (!tail) stageB(0, t0 + 2, 1);
    MM(0, 0);
    WAIT6;
    BAR;
    // ---- P5: Q(1,0); stage A1(t0+2)->buf0 ----
    RDA(1, 1);
    if (!tail) stageA(0, t0 + 2, 1);
    MM(1, 0);
    BAR;
    // ---- P6: Q(0,1); stage B0(t0+3)->buf1 ----
    RDB(1, 1); RDA(1, 0);
    if (!tail) stageB(1, t0 + 3, 0);
    MM(0, 1);
    BAR;
    // ---- P7: Q(1,1); stage A0(t0+3)->buf1 ----
    RDA(1, 1);
    if (!tail) stageA(1, t0 + 3, 0);
    MM(1, 1);
    if (!tail) asm volatile("s_waitcnt vmcnt(8)" ::: "memory");
    BAR;
  }
#undef RDA
#undef RDB
#undef MM
#undef WAIT6
#undef WAIT8
#undef BAR

  // ---- epilogue (quadrant-mapped accumulators) ----
#pragma unroll
  for (int mh = 0; mh < 2; ++mh)
#pragma unroll
    for (int nh = 0; nh < 2; ++nh)
#pragma unroll
      for (int m2 = 0; m2 < 4; ++m2)
#pragma unroll
        for (int n2 = 0; n2 < 2; ++n2) {
          int rb = m0 + mh * 128 + wm * 64 + m2 * 16 + (l >> 4) * 4;
          int col = n0 + nh * 128 + wn * 32 + n2 * 16 + (l & 15);
          f32x4 av = acc[mh][nh][m2][n2];
          if constexpr (MODE == 0) {
            int proj = col >> 10;                     // 0=Q 1=K 2=V
            int slot = ((proj == 0) ? 1 : 0) ^ tz;
            int bh = ((rb >> 10) << 4) + ((col >> 6) & 15);
            int t0q = rb & 1023;
            int dc = col & 63;
            if (proj == 2) {
              // V^T, kv' interleaved within 32-blocks: pos = j + b4*4 + q2*8
              int newoff = (t0q >> 5) * 32 + ((t0q >> 2) & 3) * 8 + ((t0q >> 4) & 1) * 4;
              u16x4v pk;
#pragma unroll
              for (int j = 0; j < 4; ++j) pk[j] = f2bf(av[j]);
              *reinterpret_cast<u16x4v*>(Vtg + (size_t)bh * 131072 +
                                         (size_t)(slot * 64 + dc) * 1024 + newoff) = pk;
            } else {
              // Q carries 0.5/sqrt(64) * log2(e) so softmax can use exp2 directly
              float sc = (proj == 0) ? 0.09016994f : 1.0f;
              u16* dstp = (proj ? Kb : Qb) + (size_t)bh * 131072 + (size_t)t0q * 128 + slot * 64 + dc;
#pragma unroll
              for (int j = 0; j < 4; ++j) dstp[(size_t)j * 128] = f2bf(av[j] * sc);
            }
          } else {
            const float* bias = tz ? by : bx;
            float* dstp = out + (size_t)tz * BT * Dd;
            float bv = bias[col];
#pragma unroll
            for (int j = 0; j < 4; ++j)
              dstp[(size_t)(rb + j) * 1024 + col] = av[j] + bv;
          }
        }
}

// ---------- flash attention: 8 waves / 128 q-rows, dbuf 2-phase pipeline ----------
// Denominator accumulated via MFMA with all-ones A-fragment (no cross-lane reduce).
__global__ __launch_bounds__(512, 4) void k_attn(const u16* __restrict__ Q,
                                                 const u16* __restrict__ K,
                                                 const u16* __restrict__ Vt,
                                                 u16* __restrict__ O) {
  __shared__ alignas(16) u16 Ks[2][8192];
  __shared__ alignas(16) u16 Vs[2][8192];
  const int tid = threadIdx.x;
  const int l = tid & 63, w = tid >> 6;
  const int bid = blockIdx.x;
  const int xcd = bid & 7, li = bid >> 3;
  const int bh = xcd + 8 * (li >> 3);    // 8 consecutive li share one bh (L2 reuse)
  const int qblk = li & 7;               // 0..7
  const int q0 = qblk * 128 + w * 16;
  const size_t base = (size_t)bh * 131072;

  bf16x8 qf[4];
#pragma unroll
  for (int dc = 0; dc < 4; ++dc)
    qf[dc] = *reinterpret_cast<const bf16x8*>(
        Q + base + (size_t)(q0 + (l & 15)) * 128 + dc * 32 + (l >> 4) * 8);

  const u16* kp[2];
  const u16* vp[2];
#pragma unroll
  for (int i = 0; i < 2; ++i) {
    int idx = i * 512 + tid;
    {
      int dc = idx >> 8, kv = (idx >> 2) & 63, pp = idx & 3, g = pp ^ ((kv >> 1) & 3);
      kp[i] = K + base + (size_t)kv * 128 + dc * 32 + g * 8;
    }
    {
      int c = idx >> 9, d = (idx >> 2) & 127, pp = idx & 3, g = pp ^ ((d >> 1) & 3);
      vp[i] = Vt + base + (size_t)d * 1024 + c * 32 + g * 8;
    }
  }
  const int i0 = tid * 8, i1 = (512 + tid) * 8;

  const int koff = (l & 15) * 32 + (((l >> 4) ^ (((l & 15) >> 1) & 3))) * 8;

  auto stage = [&](int buf, int kv0) {
    gload_lds16(kp[0] + (size_t)kv0 * 128, &Ks[buf][i0]);
    gload_lds16(kp[1] + (size_t)kv0 * 128, &Ks[buf][i1]);
    gload_lds16(vp[0] + kv0, &Vs[buf][i0]);
    gload_lds16(vp[1] + kv0, &Vs[buf][i1]);
  };

  // all-ones A fragment for denominator MFMA
  union { u16x4v u; bf16x4 v; } onesu;
#pragma unroll
  for (int j = 0; j < 4; ++j) onesu.u[j] = 0x3F80;
  const bf16x4 ones = onesu.v;

  float m_run = -3e38f;
  f32x4 Oa[8] = {};
  f32x4 Ol = {};                         // denominator accumulator

  stage(0, 0);
  __syncthreads();

  for (int t16 = 0; t16 < 16; ++t16) {
    const int cur = t16 & 1;
    if (t16 < 15) stage(cur ^ 1, (t16 + 1) * 64);

    f32x4 S[4];
    __builtin_amdgcn_s_setprio(1);
#pragma unroll
    for (int t = 0; t < 4; ++t) {
      f32x4 s = {};
#pragma unroll
      for (int dc = 0; dc < 4; ++dc) {
        bf16x8 kb = *reinterpret_cast<const bf16x8*>(&Ks[cur][dc * 2048 + t * 512 + koff]);
        s = __builtin_amdgcn_mfma_f32_16x16x32_bf16(kb, qf[dc], s, 0, 0, 0);
      }
      S[t] = s;
    }
    __builtin_amdgcn_s_setprio(0);

    float mxl = fmaxf(fmaxf(fmaxf(S[0][0], S[0][1]), fmaxf(S[0][2], S[0][3])),
                      fmaxf(fmaxf(S[1][0], S[1][1]), fmaxf(S[1][2], S[1][3])));
    float mx2 = fmaxf(fmaxf(fmaxf(S[2][0], S[2][1]), fmaxf(S[2][2], S[2][3])),
                      fmaxf(fmaxf(S[3][0], S[3][1]), fmaxf(S[3][2], S[3][3])));
    mxl = fmaxf(mxl, mx2);

    const int grow = __any(mxl > m_run + 11.0f);
    float mn = m_run;
    if (grow) {
      float mx = fmaxf(mxl, __shfl_xor(mxl, 16));
      mx = fmaxf(mx, __shfl_xor(mx, 32));
      mn = fmaxf(m_run, mx);
      float alpha = __builtin_exp2f(m_run - mn);
      m_run = mn;
      Ol *= alpha;
#pragma unroll
      for (int n = 0; n < 8; ++n) Oa[n] *= alpha;
    }
#pragma unroll
    for (int t = 0; t < 4; ++t)
#pragma unroll
      for (int j = 0; j < 4; ++j)
        S[t][j] = __builtin_exp2f(S[t][j] - mn);

    union { u32 w2[2]; bf16x4 v; } pb[4];
#pragma unroll
    for (int t = 0; t < 4; ++t) {
      pb[t].w2[0] = cvtpk(S[t][0], S[t][1]);
      pb[t].w2[1] = cvtpk(S[t][2], S[t][3]);
    }

    asm volatile("s_nop 1");
    __builtin_amdgcn_s_setprio(1);
    // denominator: Ol[.] += sum_kv P[kv][q] via all-ones A
#pragma unroll
    for (int t = 0; t < 4; ++t) Ol = MFMA16(ones, pb[t].v, Ol);
#pragma unroll
    for (int c = 0; c < 2; ++c)
#pragma unroll
      for (int n = 0; n < 8; ++n) {
        bf16x8 av = *reinterpret_cast<const bf16x8*>(&Vs[cur][c * 4096 + n * 512 + koff]);
        bf16x4 a0 = __builtin_shufflevector(av, av, 0, 1, 2, 3);
        bf16x4 a1 = __builtin_shufflevector(av, av, 4, 5, 6, 7);
        Oa[n] = MFMA16(a0, pb[2 * c].v, Oa[n]);
        Oa[n] = MFMA16(a1, pb[2 * c + 1].v, Oa[n]);
      }
    __builtin_amdgcn_s_setprio(0);

    __syncthreads();
  }
  asm volatile("s_nop 7");

  float inv = 1.0f / Ol[0];
#pragma unroll
  for (int n = 0; n < 8; ++n) {
    u16x4v pk;
#pragma unroll
    for (int j = 0; j < 4; ++j) pk[j] = f2bf(Oa[n][j] * inv);
    *reinterpret_cast<u16x4v*>(
        O + base + (size_t)(q0 + (l & 15)) * 128 + n * 16 + (l >> 4) * 4) = pk;
  }
}

// ---------- launch ----------
extern "C" void kernel_launch(void* const* d_in, const int* in_sizes, int n_in,
                              void* d_out, int out_size, void* d_ws, size_t ws_size,
                              hipStream_t stream) {
  const float* x   = (const float*)d_in[0];
  const float* y   = (const float*)d_in[1];
  const float* Wq  = (const float*)d_in[2];
  const float* Wk  = (const float*)d_in[3];
  const float* Wv  = (const float*)d_in[4];
  const float* Wox = (const float*)d_in[5];
  const float* box = (const float*)d_in[6];
  const float* Woy = (const float*)d_in[7];
  const float* boy = (const float*)d_in[8];

  u16* ws = (u16*)d_ws;
  size_t off = 0;
  u16* xb  = ws + off; off += (size_t)BT * Dd;
  u16* yb  = ws + off; off += (size_t)BT * Dd;
  u16* Wqb = ws + off; off += (size_t)Dd * Dd;   // Wq,Wk,Wv contiguous
  u16* Wkb = ws + off; off += (size_t)Dd * Dd;
  u16* Wvb = ws + off; off += (size_t)Dd * Dd;
  u16* Woxb = ws + off; off += (size_t)Dd * Dd;  // Wox,Woy contiguous
  u16* Woyb = ws + off; off += (size_t)Dd * Dd;
  (void)Wkb; (void)Wvb; (void)Woyb;
  const size_t attn_elems = (size_t)Bb * Hh * Tt * 128;
  u16* Qb = ws + off; off += attn_elems;
  u16* Kb = ws + off; off += attn_elems;
  u16* Vb = ws + off; off += attn_elems;   // V^T [bh][128][1024], kv'-interleaved
  u16* Ob = ws + off; off += attn_elems;

  k_cvt<<<dim3(512, 1, 7), dim3(256), 0, stream>>>(x, y, Wq, Wk, Wv, Wox, Woy, xb, yb, Wqb);

  k_gemm256<0, 12, 32><<<dim3(768), dim3(512), 0, stream>>>(
      xb, yb, Wqb, Qb, Kb, Vb, nullptr, nullptr, nullptr);

  k_attn<<<dim3(1024), dim3(512), 0, stream>>>(Qb, Kb, Vb, Ob);

  k_gemm256<1, 4, 32><<<dim3(256), dim3(512), 0, stream>>>(
      Ob, nullptr, Woxb, nullptr, nullptr, nullptr, box, boy, (float*)d_out);
}

// Round 22
// 263.402 us; speedup vs baseline: 1.0784x; 1.0784x over previous
//
#include <hip/hip_runtime.h>
#include <stdint.h>

#define DEV __device__ __forceinline__

typedef __bf16 bf16x8 __attribute__((ext_vector_type(8)));
typedef __bf16 bf16x4 __attribute__((ext_vector_type(4)));
typedef short s16x4 __attribute__((ext_vector_type(4)));
typedef float f32x4 __attribute__((ext_vector_type(4)));
typedef unsigned short u16;
typedef u16 u16x4v __attribute__((ext_vector_type(4)));
typedef u16 u16x8 __attribute__((ext_vector_type(8)));
typedef uint32_t u32;

static constexpr int Bb = 8, Tt = 1024, Dd = 1024, Hh = 16;
static constexpr int BT = Bb * Tt;      // 8192

// ---------- helpers ----------
DEV u16 f2bf(float f) {
  u32 u = __float_as_uint(f);
  u32 r = (u + 0x7FFFu + ((u >> 16) & 1u)) >> 16;
  return (u16)r;
}
DEV u32 cvtpk(float lo, float hi) {
  u32 r;
  asm("v_cvt_pk_bf16_f32 %0, %1, %2" : "=v"(r) : "v"(lo), "v"(hi));
  return r;
}
DEV void gload_lds16(const void* g, void* lds) {
  __builtin_amdgcn_global_load_lds(
      (const __attribute__((address_space(1))) void*)g,
      (__attribute__((address_space(3))) void*)lds,
      16, 0, 0);
}
DEV f32x4 MFMA16(bf16x4 a, bf16x4 b, f32x4 c) {
#if __has_builtin(__builtin_amdgcn_mfma_f32_16x16x16_bf16)
  return __builtin_amdgcn_mfma_f32_16x16x16_bf16(a, b, c, 0, 0, 0);
#elif __has_builtin(__builtin_amdgcn_mfma_f32_16x16x16bf16_1k)
  union { bf16x4 b; s16x4 s; } ua, ub;
  ua.b = a; ub.b = b;
  return __builtin_amdgcn_mfma_f32_16x16x16bf16_1k(ua.s, ub.s, c, 0, 0, 0);
#else
  asm("v_mfma_f32_16x16x16_bf16 %0, %1, %2, %0" : "+v"(c) : "v"(a), "v"(b));
  return c;
#endif
}

// ---------- fused converts: z=0 x, z=1 y, z=2..6 weights ----------
__global__ __launch_bounds__(256) void k_cvt(const float* __restrict__ x,
                                             const float* __restrict__ y,
                                             const float* __restrict__ Wq,
                                             const float* __restrict__ Wk,
                                             const float* __restrict__ Wv,
                                             const float* __restrict__ Wox,
                                             const float* __restrict__ Woy,
                                             u16* __restrict__ xb,
                                             u16* __restrict__ yb,
                                             u16* __restrict__ Wb) {
  const int z = blockIdx.z;
  const float* src;
  u16* dst;
  int n8;
  if (z == 0)      { src = x; dst = xb; n8 = BT * Dd / 8; }
  else if (z == 1) { src = y; dst = yb; n8 = BT * Dd / 8; }
  else {
    src = (z == 2) ? Wq : (z == 3) ? Wk : (z == 4) ? Wv : (z == 5) ? Wox : Woy;
    dst = Wb + (size_t)(z - 2) * (Dd * Dd);
    n8 = Dd * Dd / 8;
  }
  int i = blockIdx.x * blockDim.x + threadIdx.x;
  int stride = gridDim.x * blockDim.x;
  for (; i < n8; i += stride) {
    const float4* p = reinterpret_cast<const float4*>(src) + (size_t)i * 2;
    float4 a = p[0], b = p[1];
    u16x8 o;
    o[0] = f2bf(a.x); o[1] = f2bf(a.y); o[2] = f2bf(a.z); o[3] = f2bf(a.w);
    o[4] = f2bf(b.x); o[5] = f2bf(b.y); o[6] = f2bf(b.z); o[7] = f2bf(b.w);
    reinterpret_cast<u16x8*>(dst)[i] = o;
  }
}

// ---------- 256x256-tile 8-wave dbuf GEMM; 2 phases x 32 MFMA per K-tile ----------
// (round-9 schedule: split staging half0@A half1@B, lgkmcnt pins, boundary vmcnt(0))
template <int MODE, int GX, int GY>
__global__ __launch_bounds__(512, 2) void k_gemm256(
    const u16* __restrict__ xb, const u16* __restrict__ yb,
    const u16* __restrict__ W0,
    u16* __restrict__ Qb, u16* __restrict__ Kb, u16* __restrict__ Vtg,
    const float* __restrict__ bx, const float* __restrict__ by,
    float* __restrict__ out) {
  __shared__ alignas(16) u16 As[2][256 * 64];
  __shared__ alignas(16) u16 Bs[2][256 * 64];
  const int tid = threadIdx.x;
  const int l = tid & 63, wid = tid >> 6;
  const int wr = wid >> 2, wc = wid & 3;

  constexpr int NWG = GX * GY * 2;
  const int d0b = blockIdx.x;
  const int wk = (d0b & 7) * (NWG / 8) + (d0b >> 3);
  const int tz = wk / (GX * GY);
  const int rr = wk % (GX * GY);
  const int ty = rr / GX, tx = rr % GX;
  const int m0 = ty * 256, n0 = tx * 256;

  const u16* Ag;
  const u16* Wg;
  if constexpr (MODE == 0) {
    Ag = tz ? yb : xb;
    Wg = W0;
  } else {
    Ag = xb + tz * 64;                       // xb carries Ob
    Wg = W0 + (size_t)tz * (Dd * Dd);
  }

  auto stageA = [&](int buf, int kt, int half) {
#pragma unroll
    for (int i = 0; i < 2; ++i) {
      int idx = i * 512 + tid;
      int row = idx >> 3, P = idx & 7, G = P ^ (row & 7);
      const u16* src;
      if constexpr (MODE == 0) {
        src = Ag + (size_t)(m0 + half * 128 + row) * 1024 + kt * 64 + G * 8;
      } else {
        int m = m0 + half * 128 + row;
        src = Ag + ((size_t)((m >> 10) * 16 + kt) * 1024 + (m & 1023)) * 128 + G * 8;
      }
      gload_lds16(src, &As[buf][half * 8192 + idx * 8]);
    }
  };
  auto stageB = [&](int buf, int kt, int half) {
#pragma unroll
    for (int i = 0; i < 2; ++i) {
      int idx = i * 512 + tid;
      int row = idx >> 3, P = idx & 7, G = P ^ (row & 7);
      gload_lds16(Wg + (size_t)(n0 + half * 128 + row) * 1024 + kt * 64 + G * 8,
                  &Bs[buf][half * 8192 + idx * 8]);
    }
  };
  auto ldA = [&](int b, int m, int kk) -> bf16x8 {
    int row = wr * 128 + m * 16 + (l & 15);
    int P = (kk * 4 + (l >> 4)) ^ (row & 7);
    return *reinterpret_cast<const bf16x8*>(&As[b][row * 64 + P * 8]);
  };
  auto ldB = [&](int b, int n, int kk) -> bf16x8 {
    int row = wc * 64 + n * 16 + (l & 15);
    int P = (kk * 4 + (l >> 4)) ^ (row & 7);
    return *reinterpret_cast<const bf16x8*>(&Bs[b][row * 64 + P * 8]);
  };

  f32x4 acc[8][4] = {};

  // prologue: tile0 fully staged, one-time drain
  stageA(0, 0, 0); stageB(0, 0, 0); stageA(0, 0, 1); stageB(0, 0, 1);
  asm volatile("s_waitcnt vmcnt(0)" ::: "memory");
  __builtin_amdgcn_s_barrier();

  for (int kt = 0; kt < 16; ++kt) {
    const int b = kt & 1, nb = b ^ 1;
    const bool pf = kt < 15;
    bf16x8 bfr[4][2], afr[4][2];

    // ---- phase A: read all B-frags + A quads 0-3; stage next half0; 32 MFMA ----
#pragma unroll
    for (int n = 0; n < 4; ++n) { bfr[n][0] = ldB(b, n, 0); bfr[n][1] = ldB(b, n, 1); }
#pragma unroll
    for (int m = 0; m < 4; ++m) { afr[m][0] = ldA(b, m, 0); afr[m][1] = ldA(b, m, 1); }
    if (pf) { stageA(nb, kt + 1, 0); stageB(nb, kt + 1, 0); }
    __builtin_amdgcn_s_barrier();
    asm volatile("s_waitcnt lgkmcnt(0)" ::: "memory");
    __builtin_amdgcn_sched_barrier(0);
    __builtin_amdgcn_s_setprio(1);
#pragma unroll
    for (int m = 0; m < 4; ++m)
#pragma unroll
      for (int n = 0; n < 4; ++n)
#pragma unroll
        for (int kk = 0; kk < 2; ++kk)
          acc[m][n] = __builtin_amdgcn_mfma_f32_16x16x32_bf16(
              afr[m][kk], bfr[n][kk], acc[m][n], 0, 0, 0);
    __builtin_amdgcn_s_setprio(0);
    __builtin_amdgcn_s_barrier();

    // ---- phase B: read A quads 4-7 (B-frags held); stage next half1; 32 MFMA ----
#pragma unroll
    for (int m = 0; m < 4; ++m) { afr[m][0] = ldA(b, 4 + m, 0); afr[m][1] = ldA(b, 4 + m, 1); }
    if (pf) { stageA(nb, kt + 1, 1); stageB(nb, kt + 1, 1); }
    __builtin_amdgcn_s_barrier();
    asm volatile("s_waitcnt lgkmcnt(0)" ::: "memory");
    __builtin_amdgcn_sched_barrier(0);
    __builtin_amdgcn_s_setprio(1);
#pragma unroll
    for (int m = 0; m < 4; ++m)
#pragma unroll
      for (int n = 0; n < 4; ++n)
#pragma unroll
        for (int kk = 0; kk < 2; ++kk)
          acc[4 + m][n] = __builtin_amdgcn_mfma_f32_16x16x32_bf16(
              afr[m][kk], bfr[n][kk], acc[4 + m][n], 0, 0, 0);
    __builtin_amdgcn_s_setprio(0);
    // boundary: drain next-tile stage (issued >=1 phase ago), sync buffers
    asm volatile("s_waitcnt vmcnt(0)" ::: "memory");
    __builtin_amdgcn_s_barrier();
  }

  // ---- epilogue ----
#pragma unroll
  for (int m = 0; m < 8; ++m)
#pragma unroll
    for (int n = 0; n < 4; ++n) {
      int rb = m0 + wr * 128 + m * 16 + (l >> 4) * 4;
      int col = n0 + wc * 64 + n * 16 + (l & 15);
      if constexpr (MODE == 0) {
        int proj = col >> 10;                     // 0=Q 1=K 2=V
        int slot = ((proj == 0) ? 1 : 0) ^ tz;
        int bh = ((rb >> 10) << 4) + ((col >> 6) & 15);
        int t0 = rb & 1023;
        int dc = col & 63;
        if (proj == 2) {
          // V^T, kv' interleaved within 32-blocks: pos = j + b4*4 + q2*8
          int newoff = (t0 >> 5) * 32 + ((t0 >> 2) & 3) * 8 + ((t0 >> 4) & 1) * 4;
          u16x4v pk;
#pragma unroll
          for (int j = 0; j < 4; ++j) pk[j] = f2bf(acc[m][n][j]);
          *reinterpret_cast<u16x4v*>(Vtg + (size_t)bh * 131072 +
                                     (size_t)(slot * 64 + dc) * 1024 + newoff) = pk;
        } else {
          // Q carries 0.5/sqrt(64) * log2(e) so softmax can use exp2 directly
          float sc = (proj == 0) ? 0.09016994f : 1.0f;
          u16* dstp = (proj ? Kb : Qb) + (size_t)bh * 131072 + (size_t)t0 * 128 + slot * 64 + dc;
#pragma unroll
          for (int j = 0; j < 4; ++j) dstp[(size_t)j * 128] = f2bf(acc[m][n][j] * sc);
        }
      } else {
        const float* bias = tz ? by : bx;
        float* dstp = out + (size_t)tz * BT * Dd;
        float bv = bias[col];
#pragma unroll
        for (int j = 0; j < 4; ++j)
          dstp[(size_t)(rb + j) * 1024 + col] = acc[m][n][j] + bv;
      }
    }
}

// ---------- flash attention: 8 waves / 128 q-rows, dbuf 2-phase pipeline ----------
// Denominator accumulated via MFMA with all-ones A-fragment (no cross-lane reduce).
__global__ __launch_bounds__(512, 4) void k_attn(const u16* __restrict__ Q,
                                                 const u16* __restrict__ K,
                                                 const u16* __restrict__ Vt,
                                                 u16* __restrict__ O) {
  __shared__ alignas(16) u16 Ks[2][8192];
  __shared__ alignas(16) u16 Vs[2][8192];
  const int tid = threadIdx.x;
  const int l = tid & 63, w = tid >> 6;
  const int bid = blockIdx.x;
  const int xcd = bid & 7, li = bid >> 3;
  const int bh = xcd + 8 * (li >> 3);    // 8 consecutive li share one bh (L2 reuse)
  const int qblk = li & 7;               // 0..7
  const int q0 = qblk * 128 + w * 16;
  const size_t base = (size_t)bh * 131072;

  bf16x8 qf[4];
#pragma unroll
  for (int dc = 0; dc < 4; ++dc)
    qf[dc] = *reinterpret_cast<const bf16x8*>(
        Q + base + (size_t)(q0 + (l & 15)) * 128 + dc * 32 + (l >> 4) * 8);

  const u16* kp[2];
  const u16* vp[2];
#pragma unroll
  for (int i = 0; i < 2; ++i) {
    int idx = i * 512 + tid;
    {
      int dc = idx >> 8, kv = (idx >> 2) & 63, pp = idx & 3, g = pp ^ ((kv >> 1) & 3);
      kp[i] = K + base + (size_t)kv * 128 + dc * 32 + g * 8;
    }
    {
      int c = idx >> 9, d = (idx >> 2) & 127, pp = idx & 3, g = pp ^ ((d >> 1) & 3);
      vp[i] = Vt + base + (size_t)d * 1024 + c * 32 + g * 8;
    }
  }
  const int i0 = tid * 8, i1 = (512 + tid) * 8;

  const int koff = (l & 15) * 32 + (((l >> 4) ^ (((l & 15) >> 1) & 3))) * 8;

  auto stage = [&](int buf, int kv0) {
    gload_lds16(kp[0] + (size_t)kv0 * 128, &Ks[buf][i0]);
    gload_lds16(kp[1] + (size_t)kv0 * 128, &Ks[buf][i1]);
    gload_lds16(vp[0] + kv0, &Vs[buf][i0]);
    gload_lds16(vp[1] + kv0, &Vs[buf][i1]);
  };

  // all-ones A fragment for denominator MFMA
  union { u16x4v u; bf16x4 v; } onesu;
#pragma unroll
  for (int j = 0; j < 4; ++j) onesu.u[j] = 0x3F80;
  const bf16x4 ones = onesu.v;

  float m_run = -3e38f;
  f32x4 Oa[8] = {};
  f32x4 Ol = {};                         // denominator accumulator

  stage(0, 0);
  __syncthreads();

  for (int t16 = 0; t16 < 16; ++t16) {
    const int cur = t16 & 1;
    if (t16 < 15) stage(cur ^ 1, (t16 + 1) * 64);

    f32x4 S[4];
    __builtin_amdgcn_s_setprio(1);
#pragma unroll
    for (int t = 0; t < 4; ++t) {
      f32x4 s = {};
#pragma unroll
      for (int dc = 0; dc < 4; ++dc) {
        bf16x8 kb = *reinterpret_cast<const bf16x8*>(&Ks[cur][dc * 2048 + t * 512 + koff]);
        s = __builtin_amdgcn_mfma_f32_16x16x32_bf16(kb, qf[dc], s, 0, 0, 0);
      }
      S[t] = s;
    }
    __builtin_amdgcn_s_setprio(0);

    float mxl = fmaxf(fmaxf(fmaxf(S[0][0], S[0][1]), fmaxf(S[0][2], S[0][3])),
                      fmaxf(fmaxf(S[1][0], S[1][1]), fmaxf(S[1][2], S[1][3])));
    float mx2 = fmaxf(fmaxf(fmaxf(S[2][0], S[2][1]), fmaxf(S[2][2], S[2][3])),
                      fmaxf(fmaxf(S[3][0], S[3][1]), fmaxf(S[3][2], S[3][3])));
    mxl = fmaxf(mxl, mx2);

    const int grow = __any(mxl > m_run + 11.0f);
    float mn = m_run;
    if (grow) {
      float mx = fmaxf(mxl, __shfl_xor(mxl, 16));
      mx = fmaxf(mx, __shfl_xor(mx, 32));
      mn = fmaxf(m_run, mx);
      float alpha = __builtin_exp2f(m_run - mn);
      m_run = mn;
      Ol *= alpha;
#pragma unroll
      for (int n = 0; n < 8; ++n) Oa[n] *= alpha;
    }
#pragma unroll
    for (int t = 0; t < 4; ++t)
#pragma unroll
      for (int j = 0; j < 4; ++j)
        S[t][j] = __builtin_exp2f(S[t][j] - mn);

    union { u32 w2[2]; bf16x4 v; } pb[4];
#pragma unroll
    for (int t = 0; t < 4; ++t) {
      pb[t].w2[0] = cvtpk(S[t][0], S[t][1]);
      pb[t].w2[1] = cvtpk(S[t][2], S[t][3]);
    }

    asm volatile("s_nop 1");
    __builtin_amdgcn_s_setprio(1);
    // denominator: Ol[.] += sum_kv P[kv][q] via all-ones A
#pragma unroll
    for (int t = 0; t < 4; ++t) Ol = MFMA16(ones, pb[t].v, Ol);
#pragma unroll
    for (int c = 0; c < 2; ++c)
#pragma unroll
      for (int n = 0; n < 8; ++n) {
        bf16x8 av = *reinterpret_cast<const bf16x8*>(&Vs[cur][c * 4096 + n * 512 + koff]);
        bf16x4 a0 = __builtin_shufflevector(av, av, 0, 1, 2, 3);
        bf16x4 a1 = __builtin_shufflevector(av, av, 4, 5, 6, 7);
        Oa[n] = MFMA16(a0, pb[2 * c].v, Oa[n]);
        Oa[n] = MFMA16(a1, pb[2 * c + 1].v, Oa[n]);
      }
    __builtin_amdgcn_s_setprio(0);

    __syncthreads();
  }
  asm volatile("s_nop 7");

  float inv = 1.0f / Ol[0];
#pragma unroll
  for (int n = 0; n < 8; ++n) {
    u16x4v pk;
#pragma unroll
    for (int j = 0; j < 4; ++j) pk[j] = f2bf(Oa[n][j] * inv);
    *reinterpret_cast<u16x4v*>(
        O + base + (size_t)(q0 + (l & 15)) * 128 + n * 16 + (l >> 4) * 4) = pk;
  }
}

// ---------- launch ----------
extern "C" void kernel_launch(void* const* d_in, const int* in_sizes, int n_in,
                              void* d_out, int out_size, void* d_ws, size_t ws_size,
                              hipStream_t stream) {
  const float* x   = (const float*)d_in[0];
  const float* y   = (const float*)d_in[1];
  const float* Wq  = (const float*)d_in[2];
  const float* Wk  = (const float*)d_in[3];
  const float* Wv  = (const float*)d_in[4];
  const float* Wox = (const float*)d_in[5];
  const float* box = (const float*)d_in[6];
  const float* Woy = (const float*)d_in[7];
  const float* boy = (const float*)d_in[8];

  u16* ws = (u16*)d_ws;
  size_t off = 0;
  u16* xb  = ws + off; off += (size_t)BT * Dd;
  u16* yb  = ws + off; off += (size_t)BT * Dd;
  u16* Wqb = ws + off; off += (size_t)Dd * Dd;   // Wq,Wk,Wv contiguous
  u16* Wkb = ws + off; off += (size_t)Dd * Dd;
  u16* Wvb = ws + off; off += (size_t)Dd * Dd;
  u16* Woxb = ws + off; off += (size_t)Dd * Dd;  // Wox,Woy contiguous
  u16* Woyb = ws + off; off += (size_t)Dd * Dd;
  (void)Wkb; (void)Wvb; (void)Woyb;
  const size_t attn_elems = (size_t)Bb * Hh * Tt * 128;
  u16* Qb = ws + off; off += attn_elems;
  u16* Kb = ws + off; off += attn_elems;
  u16* Vb = ws + off; off += attn_elems;   // V^T [bh][128][1024], kv'-interleaved
  u16* Ob = ws + off; off += attn_elems;

  k_cvt<<<dim3(512, 1, 7), dim3(256), 0, stream>>>(x, y, Wq, Wk, Wv, Wox, Woy, xb, yb, Wqb);

  k_gemm256<0, 12, 32><<<dim3(768), dim3(512), 0, stream>>>(
      xb, yb, Wqb, Qb, Kb, Vb, nullptr, nullptr, nullptr);

  k_attn<<<dim3(1024), dim3(512), 0, stream>>>(Qb, Kb, Vb, Ob);

  k_gemm256<1, 4, 32><<<dim3(256), dim3(512), 0, stream>>>(
      Ob, nullptr, Woxb, nullptr, nullptr, nullptr, box, boy, (float*)d_out);
}